// Round 8
// baseline (1551.167 us; speedup 1.0000x reference)
//
#include <hip/hip_runtime.h>
#include <hip/hip_bf16.h>
#include <stdint.h>

#define D_MODEL_  768
#define D_LATENT_ 12288
#define N_ROWS_   16384
#define TOPK_     20
#define TOPC      32

#define BM 64
#define BN 256
#define BK 64
#define KT (D_MODEL_ / BK)     // 12
#define CTN (D_LATENT_ / BN)   // 48
#define NTHREADS 512
#define CAP 16

// LDS staging offsets (bytes): A 64x64 bf16 = 8KB, B 256x64 bf16 = 32KB
#define A_OFF 0
#define B_OFF 8192
#define STAGE_BYTES 40960      // also aliased as half tileC^T float[128][TCPAD] = 34816 B
#define TCPAD 68

typedef float f4 __attribute__((ext_vector_type(4)));
typedef short bf16x8 __attribute__((ext_vector_type(8)));

typedef const void __attribute__((address_space(1)))* gptr_t;
typedef void __attribute__((address_space(3)))* lptr_t;

__device__ __forceinline__ void stage16(const void* g, void* l) {
  __builtin_amdgcn_global_load_lds((gptr_t)g, (lptr_t)l, 16, 0, 0);
}

__device__ __forceinline__ unsigned short bf16_rne(float f) {
  unsigned u = __builtin_bit_cast(unsigned, f);
  u += 0x7FFFu + ((u >> 16) & 1u);
  return (unsigned short)(u >> 16);
}

// ---------- prep: fp32 -> bf16 ----------
__global__ void tobf16_kernel(const float4* __restrict__ in, ushort4* __restrict__ o, int n4) {
  int i = blockIdx.x * blockDim.x + threadIdx.x;
  if (i >= n4) return;
  float4 v = in[i];
  ushort4 h;
  h.x = bf16_rne(v.x); h.y = bf16_rne(v.y); h.z = bf16_rne(v.z); h.w = bf16_rne(v.w);
  o[i] = h;
}

// ---------- prep: W_dec [768][12288] -> W_decT [12288][768] ----------
__global__ void transpose_kernel(const float* __restrict__ wd, float* __restrict__ wdT) {
  __shared__ float tile[32][33];
  const int l0 = blockIdx.x * 32;
  const int d0 = blockIdx.y * 32;
  const int tx = threadIdx.x, ty = threadIdx.y;  // 32 x 8
#pragma unroll
  for (int i = 0; i < 32; i += 8)
    tile[ty + i][tx] = wd[(size_t)(d0 + ty + i) * D_LATENT_ + l0 + tx];
  __syncthreads();
#pragma unroll
  for (int i = 0; i < 32; i += 8)
    wdT[(size_t)(l0 + ty + i) * D_MODEL_ + d0 + tx] = tile[tx][ty + i];
}

// ---------- pass 1: bf16 encode GEMM + running top-32 candidate indices ----------
__global__ __launch_bounds__(NTHREADS, 4) void sae_topk(
    const unsigned short* __restrict__ xh, const unsigned short* __restrict__ wh,
    const float* __restrict__ b_enc, int* __restrict__ cand)
{
  __shared__ __align__(16) unsigned char smem[STAGE_BYTES];
  __shared__ float s_topv[BM][TOPC];
  __shared__ int   s_topi[BM][TOPC];
  __shared__ float s_thr[BM];
  __shared__ int   s_cnt[BM];
  __shared__ float s_candv[BM][CAP];
  __shared__ int   s_candi[BM][CAP];

  const int tid  = threadIdx.x;
  const int lane = tid & 63;
  const int wid  = tid >> 6;    // 0..7
  const int wm   = wid & 1;     // wave-tile row (2)
  const int wn   = wid >> 1;    // wave-tile col (4)
  const int brow = blockIdx.x * BM;

  if (tid < BM) { s_thr[tid] = -__builtin_inff(); s_cnt[tid] = 0; }
  for (int i = tid; i < BM * TOPC; i += NTHREADS) {
    (&s_topv[0][0])[i] = -__builtin_inff();
    (&s_topi[0][0])[i] = 0;
  }

  f4 acc[2][4];
#pragma unroll
  for (int m = 0; m < 2; ++m)
#pragma unroll
    for (int n = 0; n < 4; ++n) { f4 z = {0.f, 0.f, 0.f, 0.f}; acc[m][n] = z; }

  const int a_row  = tid >> 3;
  const int a_slot = tid & 7;
  const int a_goff0 = (brow + a_row) * D_MODEL_ + (a_slot ^ (a_row & 7)) * 8;

#pragma unroll 1
  for (int ct = 0; ct < CTN; ++ct) {
    // ================= GEMM over K =================
#pragma unroll 1
    for (int kt = 0; kt < KT; ++kt) {
      __syncthreads();
      stage16(xh + a_goff0 + kt * BK, smem + A_OFF + tid * 16);
#pragma unroll
      for (int j = 0; j < 4; ++j) {
        const int cid  = tid + j * 512;
        const int row  = cid >> 3;
        const int slot = cid & 7;
        const int goff = (ct * BN + row) * D_MODEL_ + kt * BK + (slot ^ (row & 7)) * 8;
        stage16(wh + goff, smem + B_OFF + wid * 1024 + j * 8192);
      }
      __syncthreads();
#pragma unroll
      for (int ks = 0; ks < 2; ++ks) {
        const int c = ks * 4 + (lane >> 4);
        bf16x8 ah[2], bh[4];
#pragma unroll
        for (int m = 0; m < 2; ++m) {
          const int row = wm * 32 + m * 16 + (lane & 15);
          ah[m] = *(const bf16x8*)(smem + A_OFF + row * 128 + ((c ^ (row & 7)) << 4));
        }
#pragma unroll
        for (int n = 0; n < 4; ++n) {
          const int col = wn * 64 + n * 16 + (lane & 15);
          bh[n] = *(const bf16x8*)(smem + B_OFF + col * 128 + ((c ^ (col & 7)) << 4));
        }
#pragma unroll
        for (int m = 0; m < 2; ++m)
#pragma unroll
          for (int n = 0; n < 4; ++n)
            acc[m][n] = __builtin_amdgcn_mfma_f32_16x16x32_bf16(ah[m], bh[n], acc[m][n], 0, 0, 0);
      }
    }
    __syncthreads();
    // ================= two half-tiles of 128 cols: dump -> scan -> insert =================
    float* tc = (float*)smem;
#pragma unroll 1
    for (int h = 0; h < 2; ++h) {
      if ((wn >> 1) == h) {
        const int cwn = wn & 1;
#pragma unroll
        for (int n = 0; n < 4; ++n) {
          const int lcol = cwn * 64 + n * 16 + (lane & 15);
          const float be = b_enc[ct * BN + h * 128 + lcol];
#pragma unroll
          for (int m = 0; m < 2; ++m) {
            const int row4 = wm * 32 + m * 16 + ((lane >> 4) << 2);
            f4 v = acc[m][n];
            v[0] += be; v[1] += be; v[2] += be; v[3] += be;
            *(f4*)(tc + lcol * TCPAD + row4) = v;
            f4 z = {0.f, 0.f, 0.f, 0.f}; acc[m][n] = z;
          }
        }
      }
      __syncthreads();
      // scan: 8 waves x 16 cols, 64 rows per wave
      {
        const int row = lane;
        const float th = s_thr[row];
        for (int i = 0; i < 16; ++i) {
          const int lcol = wid * 16 + i;
          const float v = tc[lcol * TCPAD + row];
          if (v > th) {
            const int pos = atomicAdd(&s_cnt[row], 1);
            if (pos < CAP) { s_candv[row][pos] = v; s_candi[row][pos] = ct * BN + h * 128 + lcol; }
          }
        }
      }
      __syncthreads();
      // per-row insert into running top-32
      if (tid < BM) {
        const int row = tid;
        const int nc = s_cnt[row];
        if (nc > 0) {
          float minv = s_topv[row][0]; int minp = 0;
#pragma unroll
          for (int k = 1; k < TOPC; ++k) { const float t = s_topv[row][k]; if (t < minv) { minv = t; minp = k; } }
          if (nc > CAP) {
            for (int ccol = 0; ccol < 128; ++ccol) {
              const float v = tc[ccol * TCPAD + row];
              if (v > minv) {
                s_topv[row][minp] = v; s_topi[row][minp] = ct * BN + h * 128 + ccol;
                minv = s_topv[row][0]; minp = 0;
#pragma unroll
                for (int k = 1; k < TOPC; ++k) { const float t = s_topv[row][k]; if (t < minv) { minv = t; minp = k; } }
              }
            }
          } else {
            for (int j = 0; j < nc; ++j) {
              const float v = s_candv[row][j];
              if (v > minv) {
                s_topv[row][minp] = v; s_topi[row][minp] = s_candi[row][j];
                minv = s_topv[row][0]; minp = 0;
#pragma unroll
                for (int k = 1; k < TOPC; ++k) { const float t = s_topv[row][k]; if (t < minv) { minv = t; minp = k; } }
              }
            }
          }
          s_thr[row] = minv;
          s_cnt[row] = 0;
        }
      }
      __syncthreads();
    }
  }

  // write candidate indices
  if (tid < BM) {
#pragma unroll
    for (int k = 0; k < TOPC; ++k)
      cand[(size_t)(brow + tid) * TOPC + k] = s_topi[tid][k];
  }
}

// ---------- pass 2: OpenBLAS SKYLAKEX sgemm emulation ----------
// SGEMM_DEFAULT_Q = 320; gemm_driver K-split: min_l>=2Q -> Q, else if >Q -> (min_l+1)/2.
// K=768 -> chunks {320, 224, 224}. Per C element: each chunk is a single-accumulator
// serial-ascending FMA chain; C accumulates chunk-by-chunk: C = ((a1 + a2) + a3),
// each combine one fp32 rounding. Then latents = C + b_enc (one rounding).
__device__ __forceinline__ float chunk_fma(const float* __restrict__ xr,
                                           const float* __restrict__ wr,
                                           int beg, int end) {
  float a = 0.f;
#pragma unroll 4
  for (int d0 = beg; d0 < end; d0 += 4) {
    const float4 xv = *(const float4*)(xr + d0);
    const float4 wv = *(const float4*)(wr + d0);
    a = fmaf(xv.x, wv.x, a);
    a = fmaf(xv.y, wv.y, a);
    a = fmaf(xv.z, wv.z, a);
    a = fmaf(xv.w, wv.w, a);
  }
  return a;
}

__global__ __launch_bounds__(256) void refine_decode7(
    const float* __restrict__ x, const float* __restrict__ W_enc,
    const float* __restrict__ b_enc, const int* __restrict__ cand,
    const float* __restrict__ wdT, const float* __restrict__ b_dec,
    float* __restrict__ out)
{
  __shared__ float s_selv[8][TOPK_];
  __shared__ int   s_seli[8][TOPK_];

  const int tid  = threadIdx.x;
  const int r8   = tid >> 5;          // 0..7 rows per block
  const int c    = tid & 31;          // candidate slot
  const int lane = tid & 63;
  const int row  = blockIdx.x * 8 + r8;

  const int idx = cand[(size_t)row * TOPC + c];
  const float* xr = x + (size_t)row * D_MODEL_;
  const float* wr = W_enc + (size_t)idx * D_MODEL_;

  const float a1 = chunk_fma(xr, wr, 0, 320);
  const float a2 = chunk_fma(xr, wr, 320, 544);
  const float a3 = chunk_fma(xr, wr, 544, 768);
  const float cval = (a1 + a2) + a3;       // per-chunk C += acc, two roundings
  const float val  = cval + b_enc[idx];    // bias add, one rounding

  // rank within the 32-candidate group (value desc; on equal values HIGHER index wins)
  int rank = 0;
#pragma unroll 1
  for (int s = 1; s < 32; ++s) {
    const float ov = __shfl_xor(val, s);
    const int   oi = __shfl_xor(idx, s);
    rank += (ov > val) || (ov == val && oi > idx);
  }
  const bool keep = rank < TOPK_;
  const unsigned long long m = __ballot(keep);
  const unsigned half = (unsigned)(m >> (lane & 32));
  if (keep) {
    const int pos = __popc(half & ((1u << (lane & 31)) - 1u));
    s_selv[r8][pos] = val; s_seli[r8][pos] = idx;
  }
  __syncthreads();

  // decode 8 rows: out = b_dec + sum_k v_k * W_decT[idx_k][:]  (rounding non-critical)
#pragma unroll 1
  for (int r = 0; r < 8; ++r) {
#pragma unroll
    for (int j = 0; j < 3; ++j) {
      const int d = tid + j * 256;
      float a = b_dec[d];
#pragma unroll
      for (int k = 0; k < TOPK_; ++k)
        a = fmaf(s_selv[r][k], wdT[(size_t)s_seli[r][k] * D_MODEL_ + d], a);
      out[(size_t)(blockIdx.x * 8 + r) * D_MODEL_ + d] = a;
    }
  }
}

extern "C" void kernel_launch(void* const* d_in, const int* in_sizes, int n_in,
                              void* d_out, int out_size, void* d_ws, size_t ws_size,
                              hipStream_t stream) {
  const float* x     = (const float*)d_in[0];
  const float* W_enc = (const float*)d_in[1];
  const float* b_enc = (const float*)d_in[2];
  const float* W_dec = (const float*)d_in[3];
  const float* b_dec = (const float*)d_in[4];
  float* out = (float*)d_out;
  char* ws = (char*)d_ws;

  // workspace layout (46 MB; wdT aliases xh/wh, written after sae_topk)
  unsigned short* xh = (unsigned short*)(ws + 0);          // 25165824 B
  unsigned short* wh = (unsigned short*)(ws + 25165824);   // 18874368 B -> end 44040192
  int*          candb = (int*)(ws + 44040192);             // 2097152 B  -> end 46137344
  float*         wdT = (float*)(ws + 0);                   // 37748736 B (reuses xh/wh)

  {
    int n4 = N_ROWS_ * D_MODEL_ / 4;
    tobf16_kernel<<<(n4 + 255) / 256, 256, 0, stream>>>((const float4*)x, (ushort4*)xh, n4);
  }
  {
    int n4 = D_LATENT_ * D_MODEL_ / 4;
    tobf16_kernel<<<(n4 + 255) / 256, 256, 0, stream>>>((const float4*)W_enc, (ushort4*)wh, n4);
  }

  sae_topk<<<N_ROWS_ / BM, NTHREADS, 0, stream>>>(xh, wh, b_enc, candb);

  transpose_kernel<<<dim3(D_LATENT_ / 32, D_MODEL_ / 32), dim3(32, 8), 0, stream>>>(W_dec, wdT);

  refine_decode7<<<N_ROWS_ / 8, 256, 0, stream>>>(x, W_enc, b_enc, candb, wdT, b_dec, out);
}

// Round 9
// 1155.525 us; speedup vs baseline: 1.3424x; 1.3424x over previous
//
#include <hip/hip_runtime.h>
#include <hip/hip_bf16.h>
#include <stdint.h>

#define D_MODEL_  768
#define D_LATENT_ 12288
#define N_ROWS_   16384
#define TOPK_     20
#define TOPC      24          // per column-half
#define NC        48          // total candidates per row (2 halves)

#define BM 64
#define BN 256
#define BK 64
#define KT (D_MODEL_ / BK)     // 12
#define CTH (D_LATENT_ / 2 / BN)  // 24 tiles per half
#define NTHREADS 512
#define CAP 16

// LDS staging offsets (bytes): A 64x64 bf16 = 8KB, B 256x64 bf16 = 32KB
#define A_OFF 0
#define B_OFF 8192
#define STAGE_BYTES 40960      // also aliased as half tileC^T float[128][TCPAD] = 34816 B
#define TCPAD 68

typedef float f4 __attribute__((ext_vector_type(4)));
typedef short bf16x8 __attribute__((ext_vector_type(8)));

typedef const void __attribute__((address_space(1)))* gptr_t;
typedef void __attribute__((address_space(3)))* lptr_t;

__device__ __forceinline__ void stage16(const void* g, void* l) {
  __builtin_amdgcn_global_load_lds((gptr_t)g, (lptr_t)l, 16, 0, 0);
}

__device__ __forceinline__ unsigned short bf16_rne(float f) {
  unsigned u = __builtin_bit_cast(unsigned, f);
  u += 0x7FFFu + ((u >> 16) & 1u);
  return (unsigned short)(u >> 16);
}
__device__ __forceinline__ float bf16_to_f(unsigned short h) {
  return __builtin_bit_cast(float, ((unsigned)h) << 16);
}

// ---------- prep: fp32 -> bf16 ----------
__global__ void tobf16_kernel(const float4* __restrict__ in, ushort4* __restrict__ o, int n4) {
  int i = blockIdx.x * blockDim.x + threadIdx.x;
  if (i >= n4) return;
  float4 v = in[i];
  ushort4 h;
  h.x = bf16_rne(v.x); h.y = bf16_rne(v.y); h.z = bf16_rne(v.z); h.w = bf16_rne(v.w);
  o[i] = h;
}

// ---------- prep: W_dec [768][12288] -> W_decT bf16 [12288][768] ----------
__global__ void transpose_bf16_kernel(const float* __restrict__ wd, unsigned short* __restrict__ wdT) {
  __shared__ float tile[32][33];
  const int l0 = blockIdx.x * 32;
  const int d0 = blockIdx.y * 32;
  const int tx = threadIdx.x, ty = threadIdx.y;  // 32 x 8
#pragma unroll
  for (int i = 0; i < 32; i += 8)
    tile[ty + i][tx] = wd[(size_t)(d0 + ty + i) * D_LATENT_ + l0 + tx];
  __syncthreads();
#pragma unroll
  for (int i = 0; i < 32; i += 8)
    wdT[(size_t)(l0 + ty + i) * D_MODEL_ + d0 + tx] = bf16_rne(tile[tx][ty + i]);
}

// ---------- pass 1: bf16 encode GEMM + running top-24 per column-half ----------
// grid = 512: blockIdx = rowgrp*2 + half. Two blocks/CU co-resident (LDS ~62KB).
__global__ __launch_bounds__(NTHREADS, 4) void sae_topk(
    const unsigned short* __restrict__ xh, const unsigned short* __restrict__ wh,
    const float* __restrict__ b_enc, int* __restrict__ cand)
{
  __shared__ __align__(16) unsigned char smem[STAGE_BYTES];
  __shared__ float s_topv[BM][TOPC];
  __shared__ int   s_topi[BM][TOPC];
  __shared__ float s_thr[BM];
  __shared__ int   s_cnt[BM];
  __shared__ float s_candv[BM][CAP];
  __shared__ int   s_candi[BM][CAP];

  const int tid  = threadIdx.x;
  const int lane = tid & 63;
  const int wid  = tid >> 6;    // 0..7
  const int wm   = wid & 1;     // wave-tile row (2)
  const int wn   = wid >> 1;    // wave-tile col (4)
  const int half = blockIdx.x & 1;
  const int brow = (blockIdx.x >> 1) * BM;
  const int cbase = half * (D_LATENT_ / 2);   // 0 or 6144

  if (tid < BM) { s_thr[tid] = -__builtin_inff(); s_cnt[tid] = 0; }
  for (int i = tid; i < BM * TOPC; i += NTHREADS) {
    (&s_topv[0][0])[i] = -__builtin_inff();
    (&s_topi[0][0])[i] = 0;
  }

  f4 acc[2][4];
#pragma unroll
  for (int m = 0; m < 2; ++m)
#pragma unroll
    for (int n = 0; n < 4; ++n) { f4 z = {0.f, 0.f, 0.f, 0.f}; acc[m][n] = z; }

  const int a_row  = tid >> 3;
  const int a_slot = tid & 7;
  const int a_goff0 = (brow + a_row) * D_MODEL_ + (a_slot ^ (a_row & 7)) * 8;

#pragma unroll 1
  for (int ct = 0; ct < CTH; ++ct) {
    // ================= GEMM over K =================
#pragma unroll 1
    for (int kt = 0; kt < KT; ++kt) {
      __syncthreads();
      stage16(xh + a_goff0 + kt * BK, smem + A_OFF + tid * 16);
#pragma unroll
      for (int j = 0; j < 4; ++j) {
        const int cid  = tid + j * 512;
        const int row  = cid >> 3;
        const int slot = cid & 7;
        const int goff = (cbase + ct * BN + row) * D_MODEL_ + kt * BK + (slot ^ (row & 7)) * 8;
        stage16(wh + goff, smem + B_OFF + wid * 1024 + j * 8192);
      }
      __syncthreads();
#pragma unroll
      for (int ks = 0; ks < 2; ++ks) {
        const int c = ks * 4 + (lane >> 4);
        bf16x8 ah[2], bh[4];
#pragma unroll
        for (int m = 0; m < 2; ++m) {
          const int row = wm * 32 + m * 16 + (lane & 15);
          ah[m] = *(const bf16x8*)(smem + A_OFF + row * 128 + ((c ^ (row & 7)) << 4));
        }
#pragma unroll
        for (int n = 0; n < 4; ++n) {
          const int col = wn * 64 + n * 16 + (lane & 15);
          bh[n] = *(const bf16x8*)(smem + B_OFF + col * 128 + ((c ^ (col & 7)) << 4));
        }
#pragma unroll
        for (int m = 0; m < 2; ++m)
#pragma unroll
          for (int n = 0; n < 4; ++n)
            acc[m][n] = __builtin_amdgcn_mfma_f32_16x16x32_bf16(ah[m], bh[n], acc[m][n], 0, 0, 0);
      }
    }
    __syncthreads();
    // ================= two half-tiles of 128 cols: dump -> scan -> insert =================
    float* tc = (float*)smem;
#pragma unroll 1
    for (int h = 0; h < 2; ++h) {
      if ((wn >> 1) == h) {
        const int cwn = wn & 1;
#pragma unroll
        for (int n = 0; n < 4; ++n) {
          const int lcol = cwn * 64 + n * 16 + (lane & 15);
          const float be = b_enc[cbase + ct * BN + h * 128 + lcol];
#pragma unroll
          for (int m = 0; m < 2; ++m) {
            const int row4 = wm * 32 + m * 16 + ((lane >> 4) << 2);
            f4 v = acc[m][n];
            v[0] += be; v[1] += be; v[2] += be; v[3] += be;
            *(f4*)(tc + lcol * TCPAD + row4) = v;
            f4 z = {0.f, 0.f, 0.f, 0.f}; acc[m][n] = z;
          }
        }
      }
      __syncthreads();
      // scan: 8 waves x 16 cols, 64 rows per wave
      {
        const int row = lane;
        const float th = s_thr[row];
        for (int i = 0; i < 16; ++i) {
          const int lcol = wid * 16 + i;
          const float v = tc[lcol * TCPAD + row];
          if (v > th) {
            const int pos = atomicAdd(&s_cnt[row], 1);
            if (pos < CAP) { s_candv[row][pos] = v; s_candi[row][pos] = cbase + ct * BN + h * 128 + lcol; }
          }
        }
      }
      __syncthreads();
      // per-row insert into running top-24
      if (tid < BM) {
        const int row = tid;
        const int nc = s_cnt[row];
        if (nc > 0) {
          float minv = s_topv[row][0]; int minp = 0;
#pragma unroll
          for (int k = 1; k < TOPC; ++k) { const float t = s_topv[row][k]; if (t < minv) { minv = t; minp = k; } }
          if (nc > CAP) {
            for (int ccol = 0; ccol < 128; ++ccol) {
              const float v = tc[ccol * TCPAD + row];
              if (v > minv) {
                s_topv[row][minp] = v; s_topi[row][minp] = cbase + ct * BN + h * 128 + ccol;
                minv = s_topv[row][0]; minp = 0;
#pragma unroll
                for (int k = 1; k < TOPC; ++k) { const float t = s_topv[row][k]; if (t < minv) { minv = t; minp = k; } }
              }
            }
          } else {
            for (int j = 0; j < nc; ++j) {
              const float v = s_candv[row][j];
              if (v > minv) {
                s_topv[row][minp] = v; s_topi[row][minp] = s_candi[row][j];
                minv = s_topv[row][0]; minp = 0;
#pragma unroll
                for (int k = 1; k < TOPC; ++k) { const float t = s_topv[row][k]; if (t < minv) { minv = t; minp = k; } }
              }
            }
          }
          s_thr[row] = minv;
          s_cnt[row] = 0;
        }
      }
      __syncthreads();
    }
  }

  // write candidate indices for this half
  if (tid < BM) {
#pragma unroll
    for (int k = 0; k < TOPC; ++k)
      cand[(size_t)(brow + tid) * NC + half * TOPC + k] = s_topi[tid][k];
  }
}

// ---------- pass 2: OpenBLAS SKYLAKEX sgemm emulation (K chunks {320,224,224}) ----------
__device__ __forceinline__ float chunk_fma(const float* __restrict__ xr,
                                           const float* __restrict__ wr,
                                           int beg, int end) {
  float a = 0.f;
#pragma unroll 4
  for (int d0 = beg; d0 < end; d0 += 4) {
    const float4 xv = *(const float4*)(xr + d0);
    const float4 wv = *(const float4*)(wr + d0);
    a = fmaf(xv.x, wv.x, a);
    a = fmaf(xv.y, wv.y, a);
    a = fmaf(xv.z, wv.z, a);
    a = fmaf(xv.w, wv.w, a);
  }
  return a;
}

// one 64-lane wave per row (lanes 0..47 own candidates); 4 rows per block
__global__ __launch_bounds__(256) void refine_decode8(
    const float* __restrict__ x, const float* __restrict__ W_enc,
    const float* __restrict__ b_enc, const int* __restrict__ cand,
    const unsigned short* __restrict__ wdTb, const float* __restrict__ b_dec,
    float* __restrict__ out)
{
  __shared__ float s_val[4][NC];
  __shared__ int   s_id [4][NC];
  __shared__ float s_selv[4][TOPK_];
  __shared__ int   s_seli[4][TOPK_];

  const int tid  = threadIdx.x;
  const int w    = tid >> 6;          // wave = row slot 0..3
  const int lane = tid & 63;
  const int row  = blockIdx.x * 4 + w;

  if (lane < NC) {
    const int idx = cand[(size_t)row * NC + lane];
    const float* xr = x + (size_t)row * D_MODEL_;
    const float* wr = W_enc + (size_t)idx * D_MODEL_;
    const float a1 = chunk_fma(xr, wr, 0, 320);
    const float a2 = chunk_fma(xr, wr, 320, 544);
    const float a3 = chunk_fma(xr, wr, 544, 768);
    const float val = ((a1 + a2) + a3) + b_enc[idx];
    s_val[w][lane] = val; s_id[w][lane] = idx;
  }
  __syncthreads();
  if (lane < NC) {
    const float v = s_val[w][lane]; const int id = s_id[w][lane];
    int rank = 0;
#pragma unroll 1
    for (int j = 0; j < NC; ++j) {
      const float vj = s_val[w][j]; const int ij = s_id[w][j];
      rank += (vj > v) || (vj == v && ij > id);   // hi-index wins ties
    }
    if (rank < TOPK_) { s_selv[w][rank] = v; s_seli[w][rank] = id; }
  }
  __syncthreads();

  // decode 4 rows: out = b_dec + sum_k v_k * W_decT[idx_k][:]  (bf16 wdT, non-critical)
#pragma unroll 1
  for (int r = 0; r < 4; ++r) {
#pragma unroll
    for (int j = 0; j < 3; ++j) {
      const int d = tid + j * 256;
      float a = b_dec[d];
#pragma unroll
      for (int k = 0; k < TOPK_; ++k)
        a = fmaf(s_selv[r][k], bf16_to_f(wdTb[(size_t)s_seli[r][k] * D_MODEL_ + d]), a);
      out[(size_t)(blockIdx.x * 4 + r) * D_MODEL_ + d] = a;
    }
  }
}

extern "C" void kernel_launch(void* const* d_in, const int* in_sizes, int n_in,
                              void* d_out, int out_size, void* d_ws, size_t ws_size,
                              hipStream_t stream) {
  const float* x     = (const float*)d_in[0];
  const float* W_enc = (const float*)d_in[1];
  const float* b_enc = (const float*)d_in[2];
  const float* W_dec = (const float*)d_in[3];
  const float* b_dec = (const float*)d_in[4];
  float* out = (float*)d_out;
  char* ws = (char*)d_ws;

  // workspace layout (~47 MB; wdTb aliases xh region, written after sae_topk)
  unsigned short* xh = (unsigned short*)(ws + 0);          // 25165824 B
  unsigned short* wh = (unsigned short*)(ws + 25165824);   // 18874368 B -> end 44040192
  int*          candb = (int*)(ws + 44040192);             // 16384*48*4 = 3145728 B -> end 47185920
  unsigned short* wdTb = (unsigned short*)(ws + 0);        // 18874368 B (reuses xh)

  {
    int n4 = N_ROWS_ * D_MODEL_ / 4;
    tobf16_kernel<<<(n4 + 255) / 256, 256, 0, stream>>>((const float4*)x, (ushort4*)xh, n4);
  }
  {
    int n4 = D_LATENT_ * D_MODEL_ / 4;
    tobf16_kernel<<<(n4 + 255) / 256, 256, 0, stream>>>((const float4*)W_enc, (ushort4*)wh, n4);
  }

  sae_topk<<<N_ROWS_ / BM * 2, NTHREADS, 0, stream>>>(xh, wh, b_enc, candb);

  transpose_bf16_kernel<<<dim3(D_LATENT_ / 32, D_MODEL_ / 32), dim3(32, 8), 0, stream>>>(W_dec, wdTb);

  refine_decode8<<<N_ROWS_ / 4, 256, 0, stream>>>(x, W_enc, b_enc, candb, wdTb, b_dec, out);
}

// Round 10
// 1038.649 us; speedup vs baseline: 1.4934x; 1.1125x over previous
//
#include <hip/hip_runtime.h>
#include <hip/hip_bf16.h>
#include <stdint.h>

#define D_MODEL_  768
#define D_LATENT_ 12288
#define N_ROWS_   16384
#define TOPK_     20
#define TOPC      24          // per column-half
#define NC        48          // total candidates per row (2 halves)
#define NREF      28          // candidates refined in fp32

#define BM 64
#define BN 256
#define BK 64
#define KT (D_MODEL_ / BK)       // 12
#define CTH (D_LATENT_ / 2 / BN) // 24 tiles per half
#define NTHREADS 512
#define CAP 16

// LDS staging offsets (bytes): A 64x64 bf16 = 8KB, B 256x64 bf16 = 32KB
#define A_OFF 0
#define B_OFF 8192
#define STAGE_BYTES 40960      // also aliased as half tileC^T float[128][TCPAD] = 34816 B
#define TCPAD 68

typedef float f4 __attribute__((ext_vector_type(4)));
typedef short bf16x8 __attribute__((ext_vector_type(8)));

typedef const void __attribute__((address_space(1)))* gptr_t;
typedef void __attribute__((address_space(3)))* lptr_t;

__device__ __forceinline__ void stage16(const void* g, void* l) {
  __builtin_amdgcn_global_load_lds((gptr_t)g, (lptr_t)l, 16, 0, 0);
}

__device__ __forceinline__ unsigned short bf16_rne(float f) {
  unsigned u = __builtin_bit_cast(unsigned, f);
  u += 0x7FFFu + ((u >> 16) & 1u);
  return (unsigned short)(u >> 16);
}
__device__ __forceinline__ float bf16_to_f(unsigned short h) {
  return __builtin_bit_cast(float, ((unsigned)h) << 16);
}

// ---------- prep: fp32 -> bf16 ----------
__global__ void tobf16_kernel(const float4* __restrict__ in, ushort4* __restrict__ o, int n4) {
  int i = blockIdx.x * blockDim.x + threadIdx.x;
  if (i >= n4) return;
  float4 v = in[i];
  ushort4 h;
  h.x = bf16_rne(v.x); h.y = bf16_rne(v.y); h.z = bf16_rne(v.z); h.w = bf16_rne(v.w);
  o[i] = h;
}

// ---------- prep: W_dec [768][12288] -> W_decT bf16 [12288][768] ----------
__global__ void transpose_bf16_kernel(const float* __restrict__ wd, unsigned short* __restrict__ wdT) {
  __shared__ float tile[32][33];
  const int l0 = blockIdx.x * 32;
  const int d0 = blockIdx.y * 32;
  const int tx = threadIdx.x, ty = threadIdx.y;  // 32 x 8
#pragma unroll
  for (int i = 0; i < 32; i += 8)
    tile[ty + i][tx] = wd[(size_t)(d0 + ty + i) * D_LATENT_ + l0 + tx];
  __syncthreads();
#pragma unroll
  for (int i = 0; i < 32; i += 8)
    wdT[(size_t)(l0 + ty + i) * D_MODEL_ + d0 + tx] = bf16_rne(tile[tx][ty + i]);
}

// ---------- pass 1: bf16 encode GEMM + running top-24 per column-half ----------
// grid = 512. XCD-locality remap: xcd=bid&7 (HW round-robin), 64 blocks/XCD all
// work the SAME column-half in loose lockstep -> B-tile staging is L2-shared.
__global__ __launch_bounds__(NTHREADS, 4) void sae_topk(
    const unsigned short* __restrict__ xh, const unsigned short* __restrict__ wh,
    const float* __restrict__ b_enc, int* __restrict__ candi, float* __restrict__ candv)
{
  __shared__ __align__(16) unsigned char smem[STAGE_BYTES];
  __shared__ float s_topv[BM][TOPC];
  __shared__ int   s_topi[BM][TOPC];
  __shared__ float s_thr[BM];
  __shared__ int   s_cnt[BM];
  __shared__ float s_candv[BM][CAP];
  __shared__ int   s_candi[BM][CAP];

  const int tid  = threadIdx.x;
  const int lane = tid & 63;
  const int wid  = tid >> 6;    // 0..7
  const int wm   = wid & 1;     // wave-tile row (2)
  const int wn   = wid >> 1;    // wave-tile col (4)
  const int xcd  = blockIdx.x & 7;
  const int slot = blockIdx.x >> 3;           // 0..63
  const int half = xcd >> 2;                  // XCDs 0-3 -> half 0, 4-7 -> half 1
  const int brow = ((xcd & 3) * 64 + slot) * BM;
  const int cbase = half * (D_LATENT_ / 2);   // 0 or 6144

  if (tid < BM) { s_thr[tid] = -__builtin_inff(); s_cnt[tid] = 0; }
  for (int i = tid; i < BM * TOPC; i += NTHREADS) {
    (&s_topv[0][0])[i] = -__builtin_inff();
    (&s_topi[0][0])[i] = 0;
  }

  f4 acc[2][4];
#pragma unroll
  for (int m = 0; m < 2; ++m)
#pragma unroll
    for (int n = 0; n < 4; ++n) { f4 z = {0.f, 0.f, 0.f, 0.f}; acc[m][n] = z; }

  const int a_row  = tid >> 3;
  const int a_slot = tid & 7;
  const int a_goff0 = (brow + a_row) * D_MODEL_ + (a_slot ^ (a_row & 7)) * 8;

#pragma unroll 1
  for (int ct = 0; ct < CTH; ++ct) {
    // ================= GEMM over K =================
#pragma unroll 1
    for (int kt = 0; kt < KT; ++kt) {
      __syncthreads();
      stage16(xh + a_goff0 + kt * BK, smem + A_OFF + tid * 16);
#pragma unroll
      for (int j = 0; j < 4; ++j) {
        const int cid  = tid + j * 512;
        const int row  = cid >> 3;
        const int slot2 = cid & 7;
        const int goff = (cbase + ct * BN + row) * D_MODEL_ + kt * BK + (slot2 ^ (row & 7)) * 8;
        stage16(wh + goff, smem + B_OFF + wid * 1024 + j * 8192);
      }
      __syncthreads();
#pragma unroll
      for (int ks = 0; ks < 2; ++ks) {
        const int c = ks * 4 + (lane >> 4);
        bf16x8 ah[2], bh[4];
#pragma unroll
        for (int m = 0; m < 2; ++m) {
          const int row = wm * 32 + m * 16 + (lane & 15);
          ah[m] = *(const bf16x8*)(smem + A_OFF + row * 128 + ((c ^ (row & 7)) << 4));
        }
#pragma unroll
        for (int n = 0; n < 4; ++n) {
          const int col = wn * 64 + n * 16 + (lane & 15);
          bh[n] = *(const bf16x8*)(smem + B_OFF + col * 128 + ((c ^ (col & 7)) << 4));
        }
#pragma unroll
        for (int m = 0; m < 2; ++m)
#pragma unroll
          for (int n = 0; n < 4; ++n)
            acc[m][n] = __builtin_amdgcn_mfma_f32_16x16x32_bf16(ah[m], bh[n], acc[m][n], 0, 0, 0);
      }
    }
    __syncthreads();
    // ================= two half-tiles of 128 cols: dump -> scan -> insert =================
    float* tc = (float*)smem;
#pragma unroll 1
    for (int h = 0; h < 2; ++h) {
      if ((wn >> 1) == h) {
        const int cwn = wn & 1;
#pragma unroll
        for (int n = 0; n < 4; ++n) {
          const int lcol = cwn * 64 + n * 16 + (lane & 15);
          const float be = b_enc[cbase + ct * BN + h * 128 + lcol];
#pragma unroll
          for (int m = 0; m < 2; ++m) {
            const int row4 = wm * 32 + m * 16 + ((lane >> 4) << 2);
            f4 v = acc[m][n];
            v[0] += be; v[1] += be; v[2] += be; v[3] += be;
            *(f4*)(tc + lcol * TCPAD + row4) = v;
            f4 z = {0.f, 0.f, 0.f, 0.f}; acc[m][n] = z;
          }
        }
      }
      __syncthreads();
      // scan: 8 waves x 16 cols, 64 rows per wave
      {
        const int row = lane;
        const float th = s_thr[row];
        for (int i = 0; i < 16; ++i) {
          const int lcol = wid * 16 + i;
          const float v = tc[lcol * TCPAD + row];
          if (v > th) {
            const int pos = atomicAdd(&s_cnt[row], 1);
            if (pos < CAP) { s_candv[row][pos] = v; s_candi[row][pos] = cbase + ct * BN + h * 128 + lcol; }
          }
        }
      }
      __syncthreads();
      // per-row insert into running top-24
      if (tid < BM) {
        const int row = tid;
        const int nc = s_cnt[row];
        if (nc > 0) {
          float minv = s_topv[row][0]; int minp = 0;
#pragma unroll
          for (int k = 1; k < TOPC; ++k) { const float t = s_topv[row][k]; if (t < minv) { minv = t; minp = k; } }
          if (nc > CAP) {
            for (int ccol = 0; ccol < 128; ++ccol) {
              const float v = tc[ccol * TCPAD + row];
              if (v > minv) {
                s_topv[row][minp] = v; s_topi[row][minp] = cbase + ct * BN + h * 128 + ccol;
                minv = s_topv[row][0]; minp = 0;
#pragma unroll
                for (int k = 1; k < TOPC; ++k) { const float t = s_topv[row][k]; if (t < minv) { minv = t; minp = k; } }
              }
            }
          } else {
            for (int j = 0; j < nc; ++j) {
              const float v = s_candv[row][j];
              if (v > minv) {
                s_topv[row][minp] = v; s_topi[row][minp] = s_candi[row][j];
                minv = s_topv[row][0]; minp = 0;
#pragma unroll
                for (int k = 1; k < TOPC; ++k) { const float t = s_topv[row][k]; if (t < minv) { minv = t; minp = k; } }
              }
            }
          }
          s_thr[row] = minv;
          s_cnt[row] = 0;
        }
      }
      __syncthreads();
    }
  }

  // write candidate (index, pass-1 value) for this half
  if (tid < BM) {
#pragma unroll
    for (int k = 0; k < TOPC; ++k) {
      candi[(size_t)(brow + tid) * NC + half * TOPC + k] = s_topi[tid][k];
      candv[(size_t)(brow + tid) * NC + half * TOPC + k] = s_topv[tid][k];
    }
  }
}

// ---------- pass 2: pre-rank 48 -> 28 by pass-1 values, then exact SKX fp32 refine ----------
__device__ __forceinline__ float chunk_fma(const float* __restrict__ xr,
                                           const float* __restrict__ wr,
                                           int beg, int end) {
  float a = 0.f;
#pragma unroll 4
  for (int d0 = beg; d0 < end; d0 += 4) {
    const float4 xv = *(const float4*)(xr + d0);
    const float4 wv = *(const float4*)(wr + d0);
    a = fmaf(xv.x, wv.x, a);
    a = fmaf(xv.y, wv.y, a);
    a = fmaf(xv.z, wv.z, a);
    a = fmaf(xv.w, wv.w, a);
  }
  return a;
}

// one 64-lane wave per row (lanes 0..47 own candidates); 4 rows per block
__global__ __launch_bounds__(256) void refine_decode9(
    const float* __restrict__ x, const float* __restrict__ W_enc,
    const float* __restrict__ b_enc, const int* __restrict__ candi,
    const float* __restrict__ candv,
    const unsigned short* __restrict__ wdTb, const float* __restrict__ b_dec,
    float* __restrict__ out)
{
  __shared__ float s_val[4][NC];
  __shared__ int   s_id [4][NC];
  __shared__ float s_selv[4][TOPK_];
  __shared__ int   s_seli[4][TOPK_];

  const int tid  = threadIdx.x;
  const int w    = tid >> 6;          // wave = row slot 0..3
  const int lane = tid & 63;
  const int row  = blockIdx.x * 4 + w;

  int idx = 0;
  if (lane < NC) {
    idx = candi[(size_t)row * NC + lane];
    s_val[w][lane] = candv[(size_t)row * NC + lane];
    s_id [w][lane] = idx;
  }
  __syncthreads();

  // pre-rank among 48 by pass-1 value (margin >> bf16-GEMM error)
  bool active = false;
  if (lane < NC) {
    const float v = s_val[w][lane];
    int pr = 0;
#pragma unroll 1
    for (int j = 0; j < NC; ++j) {
      const float vj = s_val[w][j];
      pr += (vj > v) || (vj == v && s_id[w][j] > idx);
    }
    active = pr < NREF;
  }
  __syncthreads();

  // exact fp32 refine (OpenBLAS SKYLAKEX: K chunks {320,224,224}, serial FMA)
  float val = -__builtin_inff();
  if (active) {
    const float* xr = x + (size_t)row * D_MODEL_;
    const float* wr = W_enc + (size_t)idx * D_MODEL_;
    const float a1 = chunk_fma(xr, wr, 0, 320);
    const float a2 = chunk_fma(xr, wr, 320, 544);
    const float a3 = chunk_fma(xr, wr, 544, 768);
    val = ((a1 + a2) + a3) + b_enc[idx];
  }
  if (lane < NC) s_val[w][lane] = val;
  __syncthreads();

  // final rank among the 28 refined (value desc; on equal values HIGHER index wins)
  if (lane < NC) {
    const float v = s_val[w][lane]; const int id = s_id[w][lane];
    if (v != -__builtin_inff()) {
      int rank = 0;
#pragma unroll 1
      for (int j = 0; j < NC; ++j) {
        const float vj = s_val[w][j];
        rank += (vj > v) || (vj == v && s_id[w][j] > id);
      }
      if (rank < TOPK_) { s_selv[w][rank] = v; s_seli[w][rank] = id; }
    }
  }
  __syncthreads();

  // decode 4 rows: out = b_dec + sum_k v_k * W_decT[idx_k][:]  (bf16 wdT, non-critical)
#pragma unroll 1
  for (int r = 0; r < 4; ++r) {
#pragma unroll
    for (int j = 0; j < 3; ++j) {
      const int d = tid + j * 256;
      float a = b_dec[d];
#pragma unroll
      for (int k = 0; k < TOPK_; ++k)
        a = fmaf(s_selv[r][k], bf16_to_f(wdTb[(size_t)s_seli[r][k] * D_MODEL_ + d]), a);
      out[(size_t)(blockIdx.x * 4 + r) * D_MODEL_ + d] = a;
    }
  }
}

extern "C" void kernel_launch(void* const* d_in, const int* in_sizes, int n_in,
                              void* d_out, int out_size, void* d_ws, size_t ws_size,
                              hipStream_t stream) {
  const float* x     = (const float*)d_in[0];
  const float* W_enc = (const float*)d_in[1];
  const float* b_enc = (const float*)d_in[2];
  const float* W_dec = (const float*)d_in[3];
  const float* b_dec = (const float*)d_in[4];
  float* out = (float*)d_out;
  char* ws = (char*)d_ws;

  // workspace layout (~50 MB; wdTb aliases xh region, written after sae_topk)
  unsigned short* xh = (unsigned short*)(ws + 0);          // 25165824 B
  unsigned short* wh = (unsigned short*)(ws + 25165824);   // 18874368 B -> end 44040192
  int*          candb = (int*)(ws + 44040192);             // 3145728 B  -> end 47185920
  float*        candvb = (float*)(ws + 47185920);          // 3145728 B  -> end 50331648
  unsigned short* wdTb = (unsigned short*)(ws + 0);        // 18874368 B (reuses xh)

  {
    int n4 = N_ROWS_ * D_MODEL_ / 4;
    tobf16_kernel<<<(n4 + 255) / 256, 256, 0, stream>>>((const float4*)x, (ushort4*)xh, n4);
  }
  {
    int n4 = D_LATENT_ * D_MODEL_ / 4;
    tobf16_kernel<<<(n4 + 255) / 256, 256, 0, stream>>>((const float4*)W_enc, (ushort4*)wh, n4);
  }

  sae_topk<<<N_ROWS_ / BM * 2, NTHREADS, 0, stream>>>(xh, wh, b_enc, candb, candvb);

  transpose_bf16_kernel<<<dim3(D_LATENT_ / 32, D_MODEL_ / 32), dim3(32, 8), 0, stream>>>(W_dec, wdTb);

  refine_decode9<<<N_ROWS_ / 4, 256, 0, stream>>>(x, W_enc, b_enc, candb, candvb, wdTb, b_dec, out);
}